// Round 15
// baseline (119.611 us; speedup 1.0000x reference)
//
#include <hip/hip_runtime.h>

// Dota2Eq3Embed round 15: dual-pipeline block. 512 threads = two 256-thread
// halves; half h processes units of side h (sid = 2*bid + h, stride 1024),
// running the verified round-9 phase cycle [P0: zFC(k-1)+A(k) | P1:
// pbuf(k-1)+G1(k) | P2: asm(k) | P3: wout(k)] offset by 2 segments between
// halves. Shared barriers pair complementary pipes across halves:
// (asm | A) and (wout | G1). Each thread's per-segment register pressure is
// identical to r9 (phases live in different WAVES, not merged in one thread
// -> no r12/r13 spill mechanism). LDS 94.5 KB -> 1 block/CU, 8 waves.

typedef __attribute__((ext_vector_type(8))) short bf16x8;
typedef __attribute__((ext_vector_type(4))) float f32x4;
typedef __attribute__((ext_vector_type(4))) unsigned u32x4;

#define DEV __device__ __forceinline__
#define MFMA __builtin_amdgcn_mfma_f32_16x16x32_bf16

DEV constexpr int pid2(int a, int b) {
  int x = a < b ? a : b, y = a < b ? b : a;
  return x * (9 - x) / 2 + y;                 // 15 pairs, lex
}
DEV constexpr int tid3(int i, int j, int k) {
  int a = i, b = j, c = k, t;
  if (a > b) { t = a; a = b; b = t; }
  if (b > c) { t = b; b = c; c = t; }
  if (a > b) { t = a; a = b; b = t; }
  return a * (a * a - 18 * a + 107) / 6 + (b - a) * (11 - a - b) / 2 + (c - b);
}
DEV ushort f2bf(float f) {                     // RTNE
  unsigned u = __builtin_bit_cast(unsigned, f);
  return (ushort)((u + 0x7FFFu + ((u >> 16) & 1u)) >> 16);
}
DEV unsigned pk2(float a, float b) {
  return (unsigned)f2bf(a) | ((unsigned)f2bf(b) << 16);
}

// ---- prep: CTfrag[side][bank][kt][nt][lane][8] bf16; WT[side][o][s]/125 ----
__global__ __launch_bounds__(256)
void prep_kernel(const float* __restrict__ c1, const float* __restrict__ c2,
                 const float* __restrict__ w1, const float* __restrict__ w2,
                 ushort* __restrict__ ctf, float* __restrict__ wt, int do_wt) {
  const int idx = blockIdx.x * 256 + threadIdx.x;
  if (idx < 131072) {
    const int e = idx & 7, l = (idx >> 3) & 63, nt = (idx >> 9) & 7,
              kt = (idx >> 12) & 1, bank = (idx >> 13) & 7, side = (idx >> 16) & 1;
    const int d = 32 * kt + 8 * (l >> 4) + e;
    const int s = 16 * nt + (l & 15);
    ctf[idx] = f2bf((side ? c2 : c1)[(d * 128 + s) * 8 + bank]);
  } else if (do_wt) {
    const int j = idx - 131072;
    if (j < 65536) {
      const int s = j & 127, o = (j >> 7) & 127, side = j >> 14;
      wt[j] = (side ? w2 : w1)[s * 128 + o] * (1.f / 125.f);
    }
  }
}

__global__ __launch_bounds__(512, 2)
void eq3_dual(const int* __restrict__ x, const float* __restrict__ embed,
              const float* __restrict__ bias1, const float* __restrict__ bias2,
              const float* __restrict__ bout1, const float* __restrict__ bout2,
              const float* __restrict__ wout1, const float* __restrict__ wout2,
              const float* __restrict__ fcw,
              const ushort* __restrict__ ctf, const float* __restrict__ wt,
              float* __restrict__ pbuf, int nunits)
{
  __shared__ ushort FT[2][80 * 64];    // per-half features, 2x10240 B
  __shared__ ushort TS[2][8 * 2184];   // per-half T, 2x34944 B
  __shared__ float  S2[2][256];
  __shared__ float  SW[2][256];
  __shared__ float  fcp[2][4];

  const int tid  = threadIdx.x;
  const int h    = tid >> 8;           // half id = side
  const int htid = tid & 255;
  const int w = htid >> 6, l = tid & 63, grp = l >> 4, lc = l & 15;

  const float*  bi    = h ? bias2 : bias1;
  const float*  bo    = h ? bout2 : bout1;
  const float*  Wf    = h ? wout2 : wout1;
  const float*  fw    = fcw + h * 256;
  const ushort* cbase = ctf + h * 65536;

  ushort* FTh = FT[h];
  ushort* TSh = TS[h];
  float*  S2h = S2[h];
  float*  SWh = SW[h];
  float*  fch = fcp[h];

  const int stride = 2 * gridDim.x;                      // 1024
  const int sid    = 2 * blockIdx.x + h;                 // stream id; side=sid&1=h
  const int nk     = (sid < nunits) ? ((nunits - 1 - sid) / stride + 1) : 0;
  const int sid0   = 2 * blockIdx.x, sid1 = sid0 + 1;
  const int nk0    = (sid0 < nunits) ? ((nunits - 1 - sid0) / stride + 1) : 0;
  const int nk1    = (sid1 < nunits) ? ((nunits - 1 - sid1) / stride + 1) : 0;
  const int Sa = 4 * nk0 + 2, Sb = 2 + 4 * nk1 + 2;
  const int S  = (Sa > Sb) ? Sa : Sb;                    // block-uniform

  // zero own FT pad rows (35..47, 63, 70..79)
  for (int e = htid; e < 24 * 64; e += 256) {
    const int r = e >> 6, d = e & 63;
    const int row = (r < 13) ? 35 + r : ((r == 13) ? 63 : 70 + (r - 14));
    FTh[(row * 64 + d) ^ ((row & 7) << 3)] = 0;
  }

  // ---------------- phase bodies (verbatim round 9, htid / per-half LDS) ----
  auto phaseA = [&](int u) {
    const int d = htid & 63, q = htid >> 6;
    const int* xn = x + u * 5;
    float v[5];
    #pragma unroll
    for (int i = 0; i < 5; ++i) v[i] = fmaxf(embed[xn[i] * 64 + d], 0.f);
    const float Sv = v[0] + v[1] + v[2] + v[3] + v[4];
    const float Sq = Sv * Sv, Sc = Sq * Sv;
    float p2a[15];
    {
      int c2 = 0;
      #pragma unroll
      for (int a = 0; a < 5; ++a)
        #pragma unroll
        for (int b = a; b < 5; ++b) { p2a[c2] = v[a] * v[b]; ++c2; }
    }
    {
      int c3 = 0;
      #pragma unroll
      for (int a = 0; a < 5; ++a)
        #pragma unroll
        for (int b = a; b < 5; ++b)
          #pragma unroll
          for (int c = b; c < 5; ++c) {
            const int qq = (c3 < 14) ? 0 : ((c3 < 28) ? 1 : 2);
            if (q == qq)
              FTh[(c3 * 64 + d) ^ ((c3 & 7) << 3)] = f2bf(p2a[pid2(a, b)] * v[c]);
            ++c3;
          }
    }
    #pragma unroll
    for (int p = 0; p < 15; ++p) {
      const int qq = (p < 7) ? 2 : 3;
      const int row = 48 + p;
      if (q == qq) FTh[(row * 64 + d) ^ ((row & 7) << 3)] = f2bf(Sv * p2a[p]);
    }
    if (q == 3) {
      #pragma unroll
      for (int i = 0; i < 5; ++i) {
        const int row = 64 + i;
        FTh[(row * 64 + d) ^ ((row & 7) << 3)] = f2bf(Sq * v[i]);
      }
      FTh[(69 * 64 + d) ^ ((69 & 7) << 3)] = f2bf(Sc);
    }
  };

  auto phaseG1 = [&]() {
    #pragma unroll
    for (int sub = 0; sub < 2; ++sub) {
      const int nti = 2 * w + sub;
      auto FR = [&](int t0, int kt) -> bf16x8 {
        const int t = t0 + lc;
        return *(const bf16x8*)(FTh + ((t * 64 + 32 * kt + 8 * grp) ^ ((t & 7) << 3)));
      };
      auto CR = [&](int bank, int kt) -> bf16x8 {
        return *(const bf16x8*)(cbase + (((bank * 2 + kt) * 8 + nti) * 64 + l) * 8);
      };
      ushort* tb = TSh + nti * 2184 + lc * 136;
      f32x4 a;
      // g0 (bank 0): t 0..34
      a = {0.f, 0.f, 0.f, 0.f};
      a = MFMA(FR(0, 0), CR(0, 0), a, 0, 0, 0);
      a = MFMA(FR(0, 1), CR(0, 1), a, 0, 0, 0);
      { uint2 t2; t2.x = pk2(a[0], a[1]); t2.y = pk2(a[2], a[3]);
        *reinterpret_cast<uint2*>(tb + 4 * grp) = t2; }
      a = {0.f, 0.f, 0.f, 0.f};
      a = MFMA(FR(16, 0), CR(0, 0), a, 0, 0, 0);
      a = MFMA(FR(16, 1), CR(0, 1), a, 0, 0, 0);
      { uint2 t2; t2.x = pk2(a[0], a[1]); t2.y = pk2(a[2], a[3]);
        *reinterpret_cast<uint2*>(tb + 16 + 4 * grp) = t2; }
      a = {0.f, 0.f, 0.f, 0.f};
      a = MFMA(FR(32, 0), CR(0, 0), a, 0, 0, 0);
      a = MFMA(FR(32, 1), CR(0, 1), a, 0, 0, 0);
      if (grp == 0) {
        *reinterpret_cast<unsigned*>(tb + 32) = pk2(a[0], a[1]);
        tb[34] = f2bf(a[2]);
      }
      // pairs (banks 1-3): t 48/64/80 + pid
      {
        const bf16x8 A0 = FR(48, 0), A1 = FR(48, 1);
        #pragma unroll
        for (int bk = 1; bk <= 3; ++bk) {
          const int cb = 48 + 16 * (bk - 1);
          a = {0.f, 0.f, 0.f, 0.f};
          a = MFMA(A0, CR(bk, 0), a, 0, 0, 0);
          a = MFMA(A1, CR(bk, 1), a, 0, 0, 0);
          if (grp < 3) {
            uint2 t2; t2.x = pk2(a[0], a[1]); t2.y = pk2(a[2], a[3]);
            *reinterpret_cast<uint2*>(tb + cb + 4 * grp) = t2;
          } else {
            *reinterpret_cast<unsigned*>(tb + cb + 12) = pk2(a[0], a[1]);
            tb[cb + 14] = f2bf(a[2]);
          }
        }
      }
      // m (banks 4-6) t 96/104/112; a7 (bank 7) t 120
      {
        const bf16x8 A0 = FR(64, 0), A1 = FR(64, 1);
        #pragma unroll
        for (int bk = 4; bk <= 6; ++bk) {
          const int cb = 96 + 8 * (bk - 4);
          a = {0.f, 0.f, 0.f, 0.f};
          a = MFMA(A0, CR(bk, 0), a, 0, 0, 0);
          a = MFMA(A1, CR(bk, 1), a, 0, 0, 0);
          if (grp == 0) {
            uint2 t2; t2.x = pk2(a[0], a[1]); t2.y = pk2(a[2], a[3]);
            *reinterpret_cast<uint2*>(tb + cb) = t2;
          } else if (grp == 1) {
            tb[cb + 4] = f2bf(a[0]);
          }
        }
        a = {0.f, 0.f, 0.f, 0.f};
        a = MFMA(A0, CR(7, 0), a, 0, 0, 0);
        a = MFMA(A1, CR(7, 1), a, 0, 0, 0);
        if (grp == 1) tb[120] = f2bf(a[1]);
      }
    }
  };

  auto phaseAsm = [&]() {
    const int ch = htid & 127, half = htid >> 7;
    const ushort* trow = TSh + (ch >> 4) * 2184 + (ch & 15) * 136;
    u32x4 R[16];
    #pragma unroll
    for (int j = 0; j < 16; ++j) R[j] = *(const u32x4*)(trow + 8 * j);
    __builtin_amdgcn_sched_barrier(0);
    auto ext = [&](int c) -> float {
      const unsigned wv = R[c >> 3][(c >> 1) & 3];
      return __builtin_bit_cast(float, (c & 1) ? (wv & 0xFFFF0000u) : (wv << 16));
    };
    const float base = ext(120) + bi[ch];
    float hs = 0.f;
    #define CELLK(i, j, k)                                                      \
      hs += fmaxf(pij + ext(96 + (k)) + ext(64 + pid2(i, k)) +                  \
                  ext(48 + pid2(j, k)) + ext(tid3(i, j, k)), 0.f);
    if (half == 0) {            // cells 0..62
      #pragma unroll
      for (int i = 0; i < 2; ++i) {
        const float pi = base + ext(112 + i);
        #pragma unroll
        for (int j = 0; j < 5; ++j) {
          const float pij = pi + ext(104 + j) + ext(80 + pid2(i, j));
          #pragma unroll
          for (int k = 0; k < 5; ++k) CELLK(i, j, k)
        }
      }
      {
        const float pi = base + ext(112 + 2);
        #pragma unroll
        for (int j = 0; j < 2; ++j) {
          const float pij = pi + ext(104 + j) + ext(80 + pid2(2, j));
          #pragma unroll
          for (int k = 0; k < 5; ++k) CELLK(2, j, k)
        }
        {
          const float pij = pi + ext(104 + 2) + ext(80 + pid2(2, 2));
          #pragma unroll
          for (int k = 0; k < 3; ++k) CELLK(2, 2, k)
        }
      }
    } else {                    // cells 63..124
      {
        const float pi = base + ext(112 + 2);
        {
          const float pij = pi + ext(104 + 2) + ext(80 + pid2(2, 2));
          #pragma unroll
          for (int k = 3; k < 5; ++k) CELLK(2, 2, k)
        }
        #pragma unroll
        for (int j = 3; j < 5; ++j) {
          const float pij = pi + ext(104 + j) + ext(80 + pid2(2, j));
          #pragma unroll
          for (int k = 0; k < 5; ++k) CELLK(2, j, k)
        }
      }
      #pragma unroll
      for (int i = 3; i < 5; ++i) {
        const float pi = base + ext(112 + i);
        #pragma unroll
        for (int j = 0; j < 5; ++j) {
          const float pij = pi + ext(104 + j) + ext(80 + pid2(i, j));
          #pragma unroll
          for (int k = 0; k < 5; ++k) CELLK(i, j, k)
        }
      }
    }
    #undef CELLK
    S2h[half * 128 + ch] = hs;
  };

  auto phaseWout = [&]() {
    const int o = htid & 127, hh = htid >> 7;
    float r;
    if (wt != nullptr) {
      const f32x4* wv = (const f32x4*)(wt + h * 16384 + o * 128 + hh * 64);
      const f32x4* pa = (const f32x4*)(S2h + hh * 64);
      const f32x4* pb = (const f32x4*)(S2h + 128 + hh * 64);
      float a0 = 0.f, a1 = 0.f, a2 = 0.f, a3 = 0.f;
      #pragma unroll
      for (int q2 = 0; q2 < 16; ++q2) {
        const f32x4 hq = pa[q2] + pb[q2];
        const f32x4 wq = wv[q2];
        a0 = fmaf(hq[0], wq[0], a0);
        a1 = fmaf(hq[1], wq[1], a1);
        a2 = fmaf(hq[2], wq[2], a2);
        a3 = fmaf(hq[3], wq[3], a3);
      }
      r = (a0 + a1) + (a2 + a3);
    } else {
      float acc = 0.f;
      #pragma unroll 8
      for (int s2 = 64 * hh; s2 < 64 * hh + 64; ++s2)
        acc = fmaf((S2h[s2] + S2h[128 + s2]) * (1.f / 125.f), Wf[s2 * 128 + o], acc);
      r = acc;
    }
    SWh[hh * 128 + o] = r;
  };

  auto phaseZFC = [&]() {
    if (htid < 128) {
      const int o = htid;
      const float z = fmaxf(SWh[o] + SWh[128 + o] + bo[o], 0.f);
      float p0 = z * fw[2 * o], p1 = z * fw[2 * o + 1];
      #pragma unroll
      for (int off = 32; off; off >>= 1) {
        p0 += __shfl_down(p0, off);
        p1 += __shfl_down(p1, off);
      }
      if ((htid & 63) == 0) { fch[(htid >> 6) * 2] = p0; fch[(htid >> 6) * 2 + 1] = p1; }
    }
  };

  // ---- segment loop: half h runs local time t = s - 2h; 2 barriers/unit ----
  for (int s = 0; s < S; ++s) {
    const int t = s - 2 * h;
    if (t >= 0 && t < 4 * nk + 2) {
      const int ph = t & 3, k = t >> 2;
      if (ph == 0) {
        if (k >= 1) phaseZFC();                        // zFC of unit k-1
        if (k < nk) phaseA(sid + stride * k);
      } else if (ph == 1) {
        if (k >= 1 && htid == 0) {
          const int up = sid + stride * (k - 1);
          pbuf[2 * up]     = fch[0] + fch[2];
          pbuf[2 * up + 1] = fch[1] + fch[3];
        }
        if (k < nk) phaseG1();
      } else if (ph == 2) {
        phaseAsm();                                    // k < nk guaranteed
      } else {
        phaseWout();
      }
    }
    __syncthreads();
  }
}

// ---------- final: out[n,c] = pbuf[2n][c] + pbuf[2n+1][c] + fcb[c] ----------
__global__ __launch_bounds__(256)
void fc_final(const float* __restrict__ pbuf, const float* __restrict__ fcb,
              float* __restrict__ out, int nout) {
  const int t = blockIdx.x * 256 + threadIdx.x;
  if (t < nout) {
    const int n = t >> 1, c = t & 1;
    out[t] = pbuf[4 * n + c] + pbuf[4 * n + 2 + c] + fcb[c];
  }
}

extern "C" void kernel_launch(void* const* d_in, const int* in_sizes, int n_in,
                              void* d_out, int out_size, void* d_ws, size_t ws_size,
                              hipStream_t stream) {
  const int*   x      = (const int*)  d_in[0];
  const float* embed  = (const float*)d_in[1];
  const float* coefs1 = (const float*)d_in[2];
  const float* bias1  = (const float*)d_in[3];
  const float* wout1  = (const float*)d_in[4];
  const float* bout1  = (const float*)d_in[5];
  const float* coefs2 = (const float*)d_in[6];
  const float* bias2  = (const float*)d_in[7];
  const float* wout2  = (const float*)d_in[8];
  const float* bout2  = (const float*)d_in[9];
  const float* fcw    = (const float*)d_in[10];
  const float* fcb    = (const float*)d_in[11];
  float* out = (float*)d_out;

  // ws: pbuf (32 KiB) | CTfrag (256 KiB) | WT (128 KiB, optional)
  float*  pbuf = (float*)d_ws;
  ushort* ctf  = (ushort*)((char*)d_ws + 32768);
  const int do_wt = (ws_size >= (size_t)(32768 + 262144 + 131072)) ? 1 : 0;
  float*  wt   = do_wt ? (float*)((char*)d_ws + 32768 + 262144) : nullptr;

  const int batch  = in_sizes[0] / 10;     // x: (B, 2, 5)
  const int nunits = batch * 2;

  prep_kernel<<<768, 256, 0, stream>>>(coefs1, coefs2, wout1, wout2, ctf, wt, do_wt);
  eq3_dual<<<512, 512, 0, stream>>>(
      x, embed, bias1, bias2, bout1, bout2, wout1, wout2, fcw, ctf, wt, pbuf, nunits);
  fc_final<<<(nunits + 255) / 256, 256, 0, stream>>>(pbuf, fcb, out, nunits);
}

// Round 16
// 92.640 us; speedup vs baseline: 1.2911x; 1.2911x over previous
//
#include <hip/hip_runtime.h>

// Dota2Eq3Embed round 16: round-9 kernel VERBATIM (verified 85.6us best:
// wave-local GEMM1 + block-uniform VALU assembly, 4 barriers/unit,
// launch_bounds(256,3)). Single change vs r9: grid 768 -> 2048 so each
// block processes exactly 2 units (4096/2048) -- r9's 5-vs-6-unit tail
// imbalance (~12% critical-path excess) removed. All else identical.

typedef __attribute__((ext_vector_type(8))) short bf16x8;
typedef __attribute__((ext_vector_type(4))) float f32x4;
typedef __attribute__((ext_vector_type(4))) unsigned u32x4;

#define DEV __device__ __forceinline__
#define MFMA __builtin_amdgcn_mfma_f32_16x16x32_bf16

DEV constexpr int pid2(int a, int b) {
  int x = a < b ? a : b, y = a < b ? b : a;
  return x * (9 - x) / 2 + y;                 // 15 pairs, lex
}
DEV constexpr int tid3(int i, int j, int k) {
  int a = i, b = j, c = k, t;
  if (a > b) { t = a; a = b; b = t; }
  if (b > c) { t = b; b = c; c = t; }
  if (a > b) { t = a; a = b; b = t; }
  return a * (a * a - 18 * a + 107) / 6 + (b - a) * (11 - a - b) / 2 + (c - b);
}
DEV ushort f2bf(float f) {                     // RTNE
  unsigned u = __builtin_bit_cast(unsigned, f);
  return (ushort)((u + 0x7FFFu + ((u >> 16) & 1u)) >> 16);
}
DEV unsigned pk2(float a, float b) {
  return (unsigned)f2bf(a) | ((unsigned)f2bf(b) << 16);
}

// ---- prep: CTfrag[side][bank][kt][nt][lane][8] bf16; WT[side][o][s]/125 ----
__global__ __launch_bounds__(256)
void prep_kernel(const float* __restrict__ c1, const float* __restrict__ c2,
                 const float* __restrict__ w1, const float* __restrict__ w2,
                 ushort* __restrict__ ctf, float* __restrict__ wt, int do_wt) {
  const int idx = blockIdx.x * 256 + threadIdx.x;
  if (idx < 131072) {
    const int e = idx & 7, l = (idx >> 3) & 63, nt = (idx >> 9) & 7,
              kt = (idx >> 12) & 1, bank = (idx >> 13) & 7, side = (idx >> 16) & 1;
    const int d = 32 * kt + 8 * (l >> 4) + e;
    const int s = 16 * nt + (l & 15);
    ctf[idx] = f2bf((side ? c2 : c1)[(d * 128 + s) * 8 + bank]);
  } else if (do_wt) {
    const int j = idx - 131072;
    if (j < 65536) {
      const int s = j & 127, o = (j >> 7) & 127, side = j >> 14;
      wt[j] = (side ? w2 : w1)[s * 128 + o] * (1.f / 125.f);
    }
  }
}

__global__ __launch_bounds__(256, 3)
void eq3_wavegemm(const int* __restrict__ x, const float* __restrict__ embed,
                  const float* __restrict__ bias1, const float* __restrict__ bias2,
                  const float* __restrict__ bout1, const float* __restrict__ bout2,
                  const float* __restrict__ wout1, const float* __restrict__ wout2,
                  const float* __restrict__ fcw,
                  const ushort* __restrict__ ctf, const float* __restrict__ wt,
                  float* __restrict__ pbuf, int nunits)
{
  __shared__ ushort FT[80 * 64];    // bf16 features, XOR-swizzled rows, 10240 B
  __shared__ ushort TS[8 * 2184];   // bf16 T, [nti][16ch][136], 34944 B
  __shared__ float  S2[256];        // asm partials [half][ch]
  __shared__ float  SW[256];        // wout partials [h][o]
  __shared__ float  fcp[4];

  const int tid = threadIdx.x;
  const int w = tid >> 6, l = tid & 63, grp = l >> 4, lc = l & 15;

  // zero FT pad rows once per block (rows 35..47, 63, 70..79)
  for (int e = tid; e < 24 * 64; e += 256) {
    const int r = e >> 6, d = e & 63;
    const int row = (r < 13) ? 35 + r : ((r == 13) ? 63 : 70 + (r - 14));
    FT[(row * 64 + d) ^ ((row & 7) << 3)] = 0;
  }
  int uprev = -1;

  for (int u = blockIdx.x; u < nunits; u += gridDim.x) {
    const int side = u & 1;

    // ================= Phase A: features -> FT (q-split rows) =================
    {
      const int d = tid & 63, q = tid >> 6;
      const int* xn = x + u * 5;
      float v[5];
      #pragma unroll
      for (int i = 0; i < 5; ++i) v[i] = fmaxf(embed[xn[i] * 64 + d], 0.f);
      const float Sv = v[0] + v[1] + v[2] + v[3] + v[4];
      const float Sq = Sv * Sv, Sc = Sq * Sv;
      float p2a[15];
      {
        int c2 = 0;
        #pragma unroll
        for (int a = 0; a < 5; ++a)
          #pragma unroll
          for (int b = a; b < 5; ++b) { p2a[c2] = v[a] * v[b]; ++c2; }
      }
      {
        int c3 = 0;
        #pragma unroll
        for (int a = 0; a < 5; ++a)
          #pragma unroll
          for (int b = a; b < 5; ++b)
            #pragma unroll
            for (int c = b; c < 5; ++c) {
              const int qq = (c3 < 14) ? 0 : ((c3 < 28) ? 1 : 2);
              if (q == qq)
                FT[(c3 * 64 + d) ^ ((c3 & 7) << 3)] = f2bf(p2a[pid2(a, b)] * v[c]);
              ++c3;
            }
      }
      #pragma unroll
      for (int p = 0; p < 15; ++p) {
        const int qq = (p < 7) ? 2 : 3;
        const int row = 48 + p;
        if (q == qq) FT[(row * 64 + d) ^ ((row & 7) << 3)] = f2bf(Sv * p2a[p]);
      }
      if (q == 3) {
        #pragma unroll
        for (int i = 0; i < 5; ++i) {
          const int row = 64 + i;
          FT[(row * 64 + d) ^ ((row & 7) << 3)] = f2bf(Sq * v[i]);
        }
        FT[(69 * 64 + d) ^ ((69 & 7) << 3)] = f2bf(Sc);
      }
    }
    __syncthreads();

    // deferred FC tail of previous unit
    if (uprev >= 0 && tid == 0) {
      pbuf[2 * uprev]     = fcp[0] + fcp[2];
      pbuf[2 * uprev + 1] = fcp[1] + fcp[3];
    }

    // ================= Phase G1: wave-local GEMM1 -> TS (bf16) =================
    {
      const ushort* cbase = ctf + side * 65536;
      #pragma unroll
      for (int sub = 0; sub < 2; ++sub) {
        const int nti = 2 * w + sub;
        auto FR = [&](int t0, int kt) -> bf16x8 {
          const int t = t0 + lc;
          return *(const bf16x8*)(FT + ((t * 64 + 32 * kt + 8 * grp) ^ ((t & 7) << 3)));
        };
        auto CR = [&](int bank, int kt) -> bf16x8 {
          return *(const bf16x8*)(cbase + (((bank * 2 + kt) * 8 + nti) * 64 + l) * 8);
        };
        ushort* tb = TS + nti * 2184 + lc * 136;
        f32x4 a;
        // g0 (bank 0): t 0..34
        a = {0.f, 0.f, 0.f, 0.f};
        a = MFMA(FR(0, 0), CR(0, 0), a, 0, 0, 0);
        a = MFMA(FR(0, 1), CR(0, 1), a, 0, 0, 0);
        { uint2 t2; t2.x = pk2(a[0], a[1]); t2.y = pk2(a[2], a[3]);
          *reinterpret_cast<uint2*>(tb + 4 * grp) = t2; }
        a = {0.f, 0.f, 0.f, 0.f};
        a = MFMA(FR(16, 0), CR(0, 0), a, 0, 0, 0);
        a = MFMA(FR(16, 1), CR(0, 1), a, 0, 0, 0);
        { uint2 t2; t2.x = pk2(a[0], a[1]); t2.y = pk2(a[2], a[3]);
          *reinterpret_cast<uint2*>(tb + 16 + 4 * grp) = t2; }
        a = {0.f, 0.f, 0.f, 0.f};
        a = MFMA(FR(32, 0), CR(0, 0), a, 0, 0, 0);
        a = MFMA(FR(32, 1), CR(0, 1), a, 0, 0, 0);
        if (grp == 0) {
          *reinterpret_cast<unsigned*>(tb + 32) = pk2(a[0], a[1]);
          tb[34] = f2bf(a[2]);
        }
        // pairs (banks 1-3): t 48/64/80 + pid
        {
          const bf16x8 A0 = FR(48, 0), A1 = FR(48, 1);
          #pragma unroll
          for (int bk = 1; bk <= 3; ++bk) {
            const int cb = 48 + 16 * (bk - 1);
            a = {0.f, 0.f, 0.f, 0.f};
            a = MFMA(A0, CR(bk, 0), a, 0, 0, 0);
            a = MFMA(A1, CR(bk, 1), a, 0, 0, 0);
            if (grp < 3) {
              uint2 t2; t2.x = pk2(a[0], a[1]); t2.y = pk2(a[2], a[3]);
              *reinterpret_cast<uint2*>(tb + cb + 4 * grp) = t2;
            } else {
              *reinterpret_cast<unsigned*>(tb + cb + 12) = pk2(a[0], a[1]);
              tb[cb + 14] = f2bf(a[2]);
            }
          }
        }
        // m (banks 4-6) t 96/104/112; a7 (bank 7) t 120
        {
          const bf16x8 A0 = FR(64, 0), A1 = FR(64, 1);
          #pragma unroll
          for (int bk = 4; bk <= 6; ++bk) {
            const int cb = 96 + 8 * (bk - 4);
            a = {0.f, 0.f, 0.f, 0.f};
            a = MFMA(A0, CR(bk, 0), a, 0, 0, 0);
            a = MFMA(A1, CR(bk, 1), a, 0, 0, 0);
            if (grp == 0) {
              uint2 t2; t2.x = pk2(a[0], a[1]); t2.y = pk2(a[2], a[3]);
              *reinterpret_cast<uint2*>(tb + cb) = t2;
            } else if (grp == 1) {
              tb[cb + 4] = f2bf(a[0]);
            }
          }
          a = {0.f, 0.f, 0.f, 0.f};
          a = MFMA(A0, CR(7, 0), a, 0, 0, 0);
          a = MFMA(A1, CR(7, 1), a, 0, 0, 0);
          if (grp == 1) tb[120] = f2bf(a[1]);
        }
      }
    }
    __syncthreads();

    // ================= Phase asm: 128 ch x 2 halves, uniform ==================
    {
      const int ch = tid & 127, half = tid >> 7;
      const ushort* trow = TS + (ch >> 4) * 2184 + (ch & 15) * 136;
      u32x4 R[16];
      #pragma unroll
      for (int j = 0; j < 16; ++j) R[j] = *(const u32x4*)(trow + 8 * j);
      __builtin_amdgcn_sched_barrier(0);
      auto ext = [&](int c) -> float {
        const unsigned wv = R[c >> 3][(c >> 1) & 3];
        return __builtin_bit_cast(float, (c & 1) ? (wv & 0xFFFF0000u) : (wv << 16));
      };
      const float* bi = side ? bias2 : bias1;
      const float base = ext(120) + bi[ch];
      float hs = 0.f;
      #define CELLK(i, j, k)                                                      \
        hs += fmaxf(pij + ext(96 + (k)) + ext(64 + pid2(i, k)) +                  \
                    ext(48 + pid2(j, k)) + ext(tid3(i, j, k)), 0.f);
      if (half == 0) {            // cells 0..62
        #pragma unroll
        for (int i = 0; i < 2; ++i) {
          const float pi = base + ext(112 + i);
          #pragma unroll
          for (int j = 0; j < 5; ++j) {
            const float pij = pi + ext(104 + j) + ext(80 + pid2(i, j));
            #pragma unroll
            for (int k = 0; k < 5; ++k) CELLK(i, j, k)
          }
        }
        {
          const float pi = base + ext(112 + 2);
          #pragma unroll
          for (int j = 0; j < 2; ++j) {
            const float pij = pi + ext(104 + j) + ext(80 + pid2(2, j));
            #pragma unroll
            for (int k = 0; k < 5; ++k) CELLK(2, j, k)
          }
          {
            const float pij = pi + ext(104 + 2) + ext(80 + pid2(2, 2));
            #pragma unroll
            for (int k = 0; k < 3; ++k) CELLK(2, 2, k)
          }
        }
      } else {                    // cells 63..124
        {
          const float pi = base + ext(112 + 2);
          {
            const float pij = pi + ext(104 + 2) + ext(80 + pid2(2, 2));
            #pragma unroll
            for (int k = 3; k < 5; ++k) CELLK(2, 2, k)
          }
          #pragma unroll
          for (int j = 3; j < 5; ++j) {
            const float pij = pi + ext(104 + j) + ext(80 + pid2(2, j));
            #pragma unroll
            for (int k = 0; k < 5; ++k) CELLK(2, j, k)
          }
        }
        #pragma unroll
        for (int i = 3; i < 5; ++i) {
          const float pi = base + ext(112 + i);
          #pragma unroll
          for (int j = 0; j < 5; ++j) {
            const float pij = pi + ext(104 + j) + ext(80 + pid2(i, j));
            #pragma unroll
            for (int k = 0; k < 5; ++k) CELLK(i, j, k)
          }
        }
      }
      #undef CELLK
      S2[half * 128 + ch] = hs;
    }
    __syncthreads();

    // ================= Phase wout: 256 thr = 128 o x 2 s-halves ===============
    {
      const int o = tid & 127, h = tid >> 7;
      float r;
      if (wt != nullptr) {
        const f32x4* wv = (const f32x4*)(wt + side * 16384 + o * 128 + h * 64);
        const f32x4* pa = (const f32x4*)(S2 + h * 64);
        const f32x4* pb = (const f32x4*)(S2 + 128 + h * 64);
        float a0 = 0.f, a1 = 0.f, a2 = 0.f, a3 = 0.f;
        #pragma unroll
        for (int q2 = 0; q2 < 16; ++q2) {
          const f32x4 hq = pa[q2] + pb[q2];
          const f32x4 wq = wv[q2];
          a0 = fmaf(hq[0], wq[0], a0);
          a1 = fmaf(hq[1], wq[1], a1);
          a2 = fmaf(hq[2], wq[2], a2);
          a3 = fmaf(hq[3], wq[3], a3);
        }
        r = (a0 + a1) + (a2 + a3);
      } else {
        const float* W = side ? wout2 : wout1;
        float acc = 0.f;
        #pragma unroll 8
        for (int s = 64 * h; s < 64 * h + 64; ++s)
          acc = fmaf((S2[s] + S2[128 + s]) * (1.f / 125.f), W[s * 128 + o], acc);
        r = acc;
      }
      SW[h * 128 + o] = r;
    }
    __syncthreads();

    // ================= Phase z/FC: partials -> fcp (no barrier) ===============
    if (tid < 128) {
      const int o = tid;
      const float* bo = side ? bout2 : bout1;
      const float z = fmaxf(SW[o] + SW[128 + o] + bo[o], 0.f);
      const float* fw = fcw + side * 256;
      float p0 = z * fw[2 * o], p1 = z * fw[2 * o + 1];
      #pragma unroll
      for (int off = 32; off; off >>= 1) {
        p0 += __shfl_down(p0, off);
        p1 += __shfl_down(p1, off);
      }
      if ((tid & 63) == 0) { fcp[(tid >> 6) * 2] = p0; fcp[(tid >> 6) * 2 + 1] = p1; }
    }
    uprev = u;
  }

  if (uprev >= 0) {
    __syncthreads();
    if (tid == 0) {
      pbuf[2 * uprev]     = fcp[0] + fcp[2];
      pbuf[2 * uprev + 1] = fcp[1] + fcp[3];
    }
  }
}

// ---------- final: out[n,c] = pbuf[2n][c] + pbuf[2n+1][c] + fcb[c] ----------
__global__ __launch_bounds__(256)
void fc_final(const float* __restrict__ pbuf, const float* __restrict__ fcb,
              float* __restrict__ out, int nout) {
  const int t = blockIdx.x * 256 + threadIdx.x;
  if (t < nout) {
    const int n = t >> 1, c = t & 1;
    out[t] = pbuf[4 * n + c] + pbuf[4 * n + 2 + c] + fcb[c];
  }
}

extern "C" void kernel_launch(void* const* d_in, const int* in_sizes, int n_in,
                              void* d_out, int out_size, void* d_ws, size_t ws_size,
                              hipStream_t stream) {
  const int*   x      = (const int*)  d_in[0];
  const float* embed  = (const float*)d_in[1];
  const float* coefs1 = (const float*)d_in[2];
  const float* bias1  = (const float*)d_in[3];
  const float* wout1  = (const float*)d_in[4];
  const float* bout1  = (const float*)d_in[5];
  const float* coefs2 = (const float*)d_in[6];
  const float* bias2  = (const float*)d_in[7];
  const float* wout2  = (const float*)d_in[8];
  const float* bout2  = (const float*)d_in[9];
  const float* fcw    = (const float*)d_in[10];
  const float* fcb    = (const float*)d_in[11];
  float* out = (float*)d_out;

  // ws: pbuf (32 KiB) | CTfrag (256 KiB) | WT (128 KiB, optional)
  float*  pbuf = (float*)d_ws;
  ushort* ctf  = (ushort*)((char*)d_ws + 32768);
  const int do_wt = (ws_size >= (size_t)(32768 + 262144 + 131072)) ? 1 : 0;
  float*  wt   = do_wt ? (float*)((char*)d_ws + 32768 + 262144) : nullptr;

  const int batch  = in_sizes[0] / 10;     // x: (B, 2, 5)
  const int nunits = batch * 2;

  prep_kernel<<<768, 256, 0, stream>>>(coefs1, coefs2, wout1, wout2, ctf, wt, do_wt);
  eq3_wavegemm<<<2048, 256, 0, stream>>>(
      x, embed, bias1, bias2, bout1, bout2, wout1, wout2, fcw, ctf, wt, pbuf, nunits);
  fc_final<<<(nunits + 255) / 256, 256, 0, stream>>>(pbuf, fcb, out, nunits);
}